// Round 7
// baseline (191.143 us; speedup 1.0000x reference)
//
#include <hip/hip_runtime.h>

// DIAGNOSTIC ROUND (correctness preserved): separate "533 MB write floor"
// from "gather-kernel inefficiency".
//   dispatch 1: pure constant fill of 533 MB into d_ws, cloning the harness
//               fillBufferAligned config (256 wg x 256 thr, grid-stride
//               dwordx4) that measures 6.9 TB/s on 2.13 GB.
//   dispatch 2: unchanged best gather (R3: tiny blocks + nt, 103.1 us).
// Same stream => graph serializes them. t_fill533 = dur_us - 103.1.
// Ladder so far: R3 103.1 | fat+plain 106.6 | fat+nt 113.6 | stride 117.2 |
// fill-clone 119.7 — all structural theories dead; this bisects H1 (fixed
// overhead / size effect) vs H2 (gather is genuinely slow).

typedef float f32x4 __attribute__((ext_vector_type(4)));

constexpr unsigned Bn = 128;
constexpr unsigned Nn = 128;
constexpr unsigned NE = Nn * (Nn - 1);   // 16256
constexpr unsigned F4 = 16;              // float4 per 64-float row
constexpr unsigned TOTAL4 = Bn * NE * F4;  // 33,292,288 f32x4 = 533 MB

// --- dispatch 1: pure 533 MB fill to d_ws (rocclr-fill-like) ---
__global__ __launch_bounds__(256) void ws_fill533(f32x4* __restrict__ ws) {
    const f32x4 v = {1.0f, 1.0f, 1.0f, 1.0f};
    unsigned stride = gridDim.x * blockDim.x;
    for (unsigned i = blockIdx.x * blockDim.x + threadIdx.x; i < TOTAL4; i += stride)
        ws[i] = v;
}

// --- dispatch 2: best-known correct gather (R3 verbatim) ---
__global__ __launch_bounds__(256) void node_edge_bcast(
    const f32x4* __restrict__ x, f32x4* __restrict__ out) {
    const unsigned blk  = blockIdx.x;        // = b*Nn + node
    const unsigned tid  = threadIdx.x;
    const unsigned f4   = tid & (F4 - 1);    // feature quad 0..15
    const unsigned row0 = tid >> 4;          // starting replica row 0..15

    const f32x4 v = x[blk * F4 + f4];

    const unsigned b    = blk >> 7;          // / Nn
    const unsigned node = blk & (Nn - 1);    // % Nn
    f32x4* dst = out + (b * NE + node * (Nn - 1)) * F4;

    #pragma unroll
    for (unsigned r = row0; r < Nn - 1; r += 16) {
        __builtin_nontemporal_store(v, &dst[r * F4 + f4]);
    }
}

extern "C" void kernel_launch(void* const* d_in, const int* in_sizes, int n_in,
                              void* d_out, int out_size, void* d_ws, size_t ws_size,
                              hipStream_t stream) {
    const f32x4* x = (const f32x4*)d_in[0];
    f32x4* out = (f32x4*)d_out;
    f32x4* ws  = (f32x4*)d_ws;

    // Diagnostic fill (only if workspace is big enough; it is ~2.13 GB).
    if (ws_size >= (size_t)TOTAL4 * sizeof(f32x4)) {
        ws_fill533<<<256, 256, 0, stream>>>(ws);
    }
    node_edge_bcast<<<Bn * Nn, 256, 0, stream>>>(x, out);
}